// Round 2
// baseline (296.625 us; speedup 1.0000x reference)
//
#include <hip/hip_runtime.h>
#include <hip/hip_bf16.h>
#include <math.h>

#define N_ATOM   100000
#define N_QUERY  20000
#define KNN      32

typedef __attribute__((ext_vector_type(8))) short  short8;
typedef __attribute__((ext_vector_type(4))) float  floatx4;

static __device__ __forceinline__ unsigned short f2bf_bits(float f) {
  union { __hip_bfloat16 h; unsigned short u; } cv;
  cv.h = __float2bfloat16(f);
  return cv.u;
}
static __device__ __forceinline__ float bflo(unsigned int u) { return __uint_as_float(u << 16); }
static __device__ __forceinline__ float bfhi(unsigned int u) { return __uint_as_float(u & 0xffff0000u); }

// ---------------- pack ALL weights into MFMA B-fragment order (bf16), one launch ----------------
// B[k][n] = (n < nsplit ? Wa[n][k] : Wb[n-nsplit][k]) * scale
// dst[((ktile*NT + ntile)*64 + lane)*8 + j] = B[ktile*32 + (lane>>4)*8 + j][ntile*16 + (lane&15)]
__global__ void pack_all_kernel(const float* __restrict__ Wq, const float* __restrict__ Wk,
                                const float* __restrict__ Wv, const float* __restrict__ W1,
                                const float* __restrict__ W2,
                                unsigned short* __restrict__ WKVp, unsigned short* __restrict__ WQp,
                                unsigned short* __restrict__ W1p,  unsigned short* __restrict__ W2p) {
  int tid = blockIdx.x * blockDim.x + threadIdx.x;
  if (tid >= 98304) return;
  const float *Wa, *Wb; int nsplit, Kd, Nd; unsigned short* dst; float scale = 1.0f;
  int t = tid;
  if (t < 32768)      { Wa = Wk; Wb = Wv; nsplit = 128; Kd = 128; Nd = 256; dst = WKVp; }
  else if (t < 49152) { t -= 32768; Wa = Wq; Wb = Wq; nsplit = 128; Kd = 128; Nd = 128; dst = WQp; scale = 0.25f; }
  else if (t < 81920) { t -= 49152; Wa = W1; Wb = W1; nsplit = 128; Kd = 256; Nd = 128; dst = W1p; }
  else                { t -= 81920; Wa = W2; Wb = W2; nsplit = 128; Kd = 128; Nd = 128; dst = W2p; }
  int j    = t & 7;
  int lane = (t >> 3) & 63;
  int t2   = t >> 9;
  int NT   = Nd >> 4;
  int ntile = t2 % NT;
  int ktile = t2 / NT;
  int k = ktile * 32 + (lane >> 4) * 8 + j;
  int n = ntile * 16 + (lane & 15);
  float v = (n < nsplit) ? Wa[(size_t)n * Kd + k] : Wb[(size_t)(n - nsplit) * Kd + k];
  dst[t] = f2bf_bits(v * scale);
}

// ---------------- MFMA GEMM: OUT[M][NT*16] = bf16(A[M][KD]) @ Bpack ----------------
// MT row-tiles of 16 per wave (B-frag reused MT times).
// SPLIT: KD==256, first 128 cols from A (stride 128), last 128 from A2 (stride 128).
// EPI 0: store bf16.  EPI 1: relu(x + bias) -> fp32.  EPI 2: x + bias + resid, LayerNorm -> fp32.
template<int KD, int NT, int MT, int EPI, bool SPLIT>
__global__ __launch_bounds__(256) void gemm_k(
    const float* __restrict__ A, const float* __restrict__ A2,
    const unsigned short* __restrict__ Bp, int M,
    unsigned short* __restrict__ outb, float* __restrict__ outf,
    const float* __restrict__ bias, const float* __restrict__ resid,
    const float* __restrict__ gamma, const float* __restrict__ beta) {
  constexpr int ND = NT * 16;
  const int l    = threadIdx.x & 63;
  const int w    = threadIdx.x >> 6;
  const int quad = l >> 4;
  const int col0 = l & 15;
  const int row0 = blockIdx.x * (4 * MT * 16) + w * (MT * 16);
  int arow[MT];
#pragma unroll
  for (int mt = 0; mt < MT; mt++) {
    int r = row0 + mt * 16 + col0;
    arow[mt] = (r < M) ? r : (M - 1);
  }

  floatx4 acc[MT][NT];
#pragma unroll
  for (int mt = 0; mt < MT; mt++)
#pragma unroll
    for (int nt = 0; nt < NT; nt++) acc[mt][nt] = (floatx4){0.f, 0.f, 0.f, 0.f};

#pragma unroll
  for (int k0 = 0; k0 < KD; k0 += 32) {
    short8 af[MT];
#pragma unroll
    for (int mt = 0; mt < MT; mt++) {
      const float* sp;
      int ks;
      if (SPLIT && k0 >= 128) { sp = A2 + (size_t)arow[mt] * 128; ks = k0 - 128; }
      else                    { sp = A  + (size_t)arow[mt] * (SPLIT ? 128 : KD); ks = k0; }
      floatx4 a0 = *(const floatx4*)(sp + ks + quad * 8);
      floatx4 a1 = *(const floatx4*)(sp + ks + quad * 8 + 4);
      af[mt][0] = (short)f2bf_bits(a0[0]); af[mt][1] = (short)f2bf_bits(a0[1]);
      af[mt][2] = (short)f2bf_bits(a0[2]); af[mt][3] = (short)f2bf_bits(a0[3]);
      af[mt][4] = (short)f2bf_bits(a1[0]); af[mt][5] = (short)f2bf_bits(a1[1]);
      af[mt][6] = (short)f2bf_bits(a1[2]); af[mt][7] = (short)f2bf_bits(a1[3]);
    }
    const unsigned short* bbase = Bp + (size_t)(k0 >> 5) * NT * 512 + l * 8;
#pragma unroll
    for (int nt = 0; nt < NT; nt++) {
      short8 bf = *(const short8*)(bbase + nt * 512);
#pragma unroll
      for (int mt = 0; mt < MT; mt++)
        acc[mt][nt] = __builtin_amdgcn_mfma_f32_16x16x32_bf16(af[mt], bf, acc[mt][nt], 0, 0, 0);
    }
  }

#pragma unroll
  for (int mt = 0; mt < MT; mt++) {
    const int rb = row0 + mt * 16;
    if (EPI == 0) {
#pragma unroll
      for (int nt = 0; nt < NT; nt++) {
#pragma unroll
        for (int r = 0; r < 4; r++) {
          int row = rb + quad * 4 + r;   // C/D: row = (lane>>4)*4 + reg, col = lane&15
          if (row < M) outb[(size_t)row * ND + nt * 16 + col0] = f2bf_bits(acc[mt][nt][r]);
        }
      }
    } else if (EPI == 1) {
#pragma unroll
      for (int nt = 0; nt < NT; nt++) {
#pragma unroll
        for (int r = 0; r < 4; r++) {
          int row = rb + quad * 4 + r;
          if (row < M) {
            int c = nt * 16 + col0;
            float v = acc[mt][nt][r] + bias[c];
            outf[(size_t)row * ND + c] = fmaxf(v, 0.f);
          }
        }
      }
    } else {
      // LayerNorm epilogue: requires ND == 128
#pragma unroll
      for (int r = 0; r < 4; r++) {
        int row = rb + quad * 4 + r;
        int rr  = row < M ? row : M - 1;
        float v[NT];
        float s1 = 0.f, s2 = 0.f;
#pragma unroll
        for (int nt = 0; nt < NT; nt++) {
          int c = nt * 16 + col0;
          v[nt] = acc[mt][nt][r] + bias[c] + resid[(size_t)rr * ND + c];
          s1 += v[nt];
        }
        s1 += __shfl_xor(s1, 1, 64); s1 += __shfl_xor(s1, 2, 64);
        s1 += __shfl_xor(s1, 4, 64); s1 += __shfl_xor(s1, 8, 64);
#pragma unroll
        for (int nt = 0; nt < NT; nt++) s2 += v[nt] * v[nt];
        s2 += __shfl_xor(s2, 1, 64); s2 += __shfl_xor(s2, 2, 64);
        s2 += __shfl_xor(s2, 4, 64); s2 += __shfl_xor(s2, 8, 64);
        float mean = s1 * (1.0f / ND);
        float var  = s2 * (1.0f / ND) - mean * mean;
        float rstd = rsqrtf(var + 1e-5f);
        if (row < M) {
#pragma unroll
          for (int nt = 0; nt < NT; nt++) {
            int c = nt * 16 + col0;
            outf[(size_t)row * ND + c] = (v[nt] - mean) * rstd * gamma[c] + beta[c];
          }
        }
      }
    }
  }
}

// ---------------- attention: one wave per query, full register prefetch, no-max softmax ----------
// Scores here are bounded (|score| ~ a few units); softmax is shift-invariant so skipping the
// max subtraction is exact in infinite precision and safe in fp32 (exp overflows only past ~87).
__global__ __launch_bounds__(256) void attn_kernel(
    const unsigned short* __restrict__ Qb,    // [N_QUERY][128] bf16 (pre-scaled by 1/sqrt(16))
    const unsigned short* __restrict__ KVb,   // [N_ATOM][256] bf16 (K | V)
    const float* __restrict__ edge_attr,      // [E][16]
    const float* __restrict__ Wrbf,           // [8][16]
    const int* __restrict__ src,              // [E]
    float* __restrict__ Agg) {                // [N_QUERY][128]
  const int l = threadIdx.x & 63;
  const int w = threadIdx.x >> 6;
  const int q = blockIdx.x * 4 + w;
  const int h  = l >> 3;          // head owning dims 2l,2l+1
  const int r8 = l & 7;

  unsigned int qu = ((const unsigned int*)(Qb + (size_t)q * 128))[l];
  float q0 = bflo(qu);
  float q1 = bfhi(qu);
  float2 wr = *(const float2*)(Wrbf + h * 16 + 2 * r8);

  const int e0 = q * KNN;
  int srcj = (l < KNN) ? src[e0 + l] : 0;

  unsigned int ku[KNN], vu[KNN];
  float2 ea[KNN];
#pragma unroll
  for (int j = 0; j < KNN; j++) {
    int s = __shfl(srcj, j, 64);
    const unsigned int* kvp = (const unsigned int*)(KVb + (size_t)s * 256);
    ku[j] = kvp[l];
    vu[j] = kvp[64 + l];
  }
#pragma unroll
  for (int j = 0; j < KNN; j++)
    ea[j] = *(const float2*)(edge_attr + (size_t)(e0 + j) * 16 + 2 * r8);

  float lsum = 0.f, acc0 = 0.f, acc1 = 0.f;
#pragma unroll
  for (int j = 0; j < KNN; j++) {
    float part = q0 * bflo(ku[j]) + q1 * bfhi(ku[j]) + wr.x * ea[j].x + wr.y * ea[j].y;
    part += __shfl_xor(part, 1, 64);
    part += __shfl_xor(part, 2, 64);
    part += __shfl_xor(part, 4, 64);   // 8 lanes of the head group now hold score[j][h]
    float p = __expf(part);
    lsum += p;
    acc0 += p * bflo(vu[j]);
    acc1 += p * bfhi(vu[j]);
  }
  float inv = 1.f / (lsum + 1e-16f);
  float2 ag; ag.x = acc0 * inv; ag.y = acc1 * inv;
  *(float2*)(Agg + (size_t)q * 128 + 2 * l) = ag;
}

extern "C" void kernel_launch(void* const* d_in, const int* in_sizes, int n_in,
                              void* d_out, int out_size, void* d_ws, size_t ws_size,
                              hipStream_t stream) {
  const float* h_atom    = (const float*)d_in[0];
  const float* h_query   = (const float*)d_in[1];
  const float* edge_attr = (const float*)d_in[2];
  const float* W_q  = (const float*)d_in[3];
  const float* W_k  = (const float*)d_in[4];
  const float* W_v  = (const float*)d_in[5];
  const float* Wrbf = (const float*)d_in[6];
  const float* W1   = (const float*)d_in[7];
  const float* b1   = (const float*)d_in[8];
  const float* W2   = (const float*)d_in[9];
  const float* b2   = (const float*)d_in[10];
  const float* ln_g = (const float*)d_in[11];
  const float* ln_b = (const float*)d_in[12];
  const int* edge_index = (const int*)d_in[13];   // [0..E) = src
  float* out = (float*)d_out;

  char* ws = (char*)d_ws;
  unsigned short* KVb = (unsigned short*)(ws);                 // 100000*256 bf16 = 51.2 MB
  unsigned short* Qb  = (unsigned short*)(ws + 51200000);      // 20000*128 bf16 = 5.12 MB
  float* Agg  = (float*)(ws + 56320000);                       // 20000*128 f32  = 10.24 MB
  float* Hbuf = (float*)(ws + 66560000);                       // 20000*128 f32  = 10.24 MB
  unsigned short* WKVp = (unsigned short*)(ws + 76800000);     // 128x256
  unsigned short* WQp  = WKVp + 32768;                         // 128x128
  unsigned short* W1p  = WQp  + 16384;                         // 256x128
  unsigned short* W2p  = W1p  + 32768;                         // 128x128

  pack_all_kernel<<<(98304 + 255) / 256, 256, 0, stream>>>(
      W_q, W_k, W_v, W1, W2, WKVp, WQp, W1p, W2p);

  // KV = h_atom @ [W_k|W_v]^T  -> bf16 [N_ATOM][256]
  gemm_k<128, 16, 2, 0, false><<<(N_ATOM + 127) / 128, 256, 0, stream>>>(
      h_atom, nullptr, WKVp, N_ATOM, KVb, nullptr, nullptr, nullptr, nullptr, nullptr);
  // Q = h_query @ (W_q/4)^T -> bf16 [N_QUERY][128]
  gemm_k<128, 8, 2, 0, false><<<(N_QUERY + 127) / 128, 256, 0, stream>>>(
      h_query, nullptr, WQp, N_QUERY, Qb, nullptr, nullptr, nullptr, nullptr, nullptr);
  // attention -> Agg
  attn_kernel<<<N_QUERY / 4, 256, 0, stream>>>(Qb, KVb, edge_attr, Wrbf, edge_index, Agg);
  // hidden = relu([h_query | agg] @ W1^T + b1) -> fp32  (split-K A operand)
  gemm_k<256, 8, 2, 1, true><<<(N_QUERY + 127) / 128, 256, 0, stream>>>(
      h_query, Agg, W1p, N_QUERY, nullptr, Hbuf, b1, nullptr, nullptr, nullptr);
  // out = LN(hidden @ W2^T + b2 + h_query)
  gemm_k<128, 8, 2, 2, false><<<(N_QUERY + 127) / 128, 256, 0, stream>>>(
      Hbuf, nullptr, W2p, N_QUERY, nullptr, out, b2, h_query, ln_g, ln_b);
}

// Round 3
// 243.941 us; speedup vs baseline: 1.2160x; 1.2160x over previous
//
#include <hip/hip_runtime.h>
#include <hip/hip_bf16.h>
#include <math.h>

#define N_ATOM   100000
#define N_QUERY  20000
#define KNN      32

typedef __attribute__((ext_vector_type(8))) short  short8;
typedef __attribute__((ext_vector_type(4))) float  floatx4;
typedef __attribute__((ext_vector_type(2))) float  fx2;

static __device__ __forceinline__ unsigned short f2bf_bits(float f) {
  union { __hip_bfloat16 h; unsigned short u; } cv;
  cv.h = __float2bfloat16(f);
  return cv.u;
}
static __device__ __forceinline__ float bflo(unsigned int u) { return __uint_as_float(u << 16); }
static __device__ __forceinline__ float bfhi(unsigned int u) { return __uint_as_float(u & 0xffff0000u); }

// ---------------- pack ALL weights into MFMA B-fragment order (bf16), one launch ----------------
// dst[((ktile*NT + ntile)*64 + lane)*8 + j] = W^T[ktile*32 + (lane>>4)*8 + j][ntile*16 + (lane&15)]
__global__ void pack_all_kernel(const float* __restrict__ Wq, const float* __restrict__ Wk,
                                const float* __restrict__ Wv, const float* __restrict__ W1,
                                const float* __restrict__ W2,
                                unsigned short* __restrict__ WKVp, unsigned short* __restrict__ WQp,
                                unsigned short* __restrict__ W1p,  unsigned short* __restrict__ W2p) {
  int tid = blockIdx.x * blockDim.x + threadIdx.x;
  if (tid >= 98304) return;
  const float *Wa, *Wb; int nsplit, Kd, Nd; unsigned short* dst; float scale = 1.0f;
  int t = tid;
  if (t < 32768)      { Wa = Wk; Wb = Wv; nsplit = 128; Kd = 128; Nd = 256; dst = WKVp; }
  else if (t < 49152) { t -= 32768; Wa = Wq; Wb = Wq; nsplit = 128; Kd = 128; Nd = 128; dst = WQp; scale = 0.25f; }
  else if (t < 81920) { t -= 49152; Wa = W1; Wb = W1; nsplit = 128; Kd = 256; Nd = 128; dst = W1p; }
  else                { t -= 81920; Wa = W2; Wb = W2; nsplit = 128; Kd = 128; Nd = 128; dst = W2p; }
  int j    = t & 7;
  int lane = (t >> 3) & 63;
  int t2   = t >> 9;
  int NT   = Nd >> 4;
  int ntile = t2 % NT;
  int ktile = t2 / NT;
  int k = ktile * 32 + (lane >> 4) * 8 + j;
  int n = ntile * 16 + (lane & 15);
  float v = (n < nsplit) ? Wa[(size_t)n * Kd + k] : Wb[(size_t)(n - nsplit) * Kd + k];
  dst[t] = f2bf_bits(v * scale);
}

// ---------------- MFMA GEMM (MT=1): OUT[M][NT*16] = bf16(A[M][KD]) @ Bpack ----------------
// EPI 0: store bf16 to outb.
// EPI 3: NT==16 KV split — cols 0..127 -> fp8 e4m3 (outp8), cols 128..255 -> bf16 (outb).
template<int KD, int NT, int EPI>
__global__ __launch_bounds__(256) void gemm_k(
    const float* __restrict__ A, const unsigned short* __restrict__ Bp, int M,
    unsigned short* __restrict__ outb, unsigned char* __restrict__ outp8) {
  constexpr int ND = NT * 16;
  const int l    = threadIdx.x & 63;
  const int w    = threadIdx.x >> 6;
  const int quad = l >> 4;
  const int col0 = l & 15;
  const int row0 = blockIdx.x * 64 + w * 16;
  int arow = row0 + col0;
  if (arow >= M) arow = M - 1;

  floatx4 acc[NT];
#pragma unroll
  for (int i = 0; i < NT; i++) acc[i] = (floatx4){0.f, 0.f, 0.f, 0.f};

  const float* aptr = A + (size_t)arow * KD + quad * 8;
#pragma unroll
  for (int k0 = 0; k0 < KD; k0 += 32) {
    floatx4 a0 = *(const floatx4*)(aptr + k0);
    floatx4 a1 = *(const floatx4*)(aptr + k0 + 4);
    short8 af;
    af[0] = (short)f2bf_bits(a0[0]); af[1] = (short)f2bf_bits(a0[1]);
    af[2] = (short)f2bf_bits(a0[2]); af[3] = (short)f2bf_bits(a0[3]);
    af[4] = (short)f2bf_bits(a1[0]); af[5] = (short)f2bf_bits(a1[1]);
    af[6] = (short)f2bf_bits(a1[2]); af[7] = (short)f2bf_bits(a1[3]);
    const unsigned short* bbase = Bp + (size_t)(k0 >> 5) * NT * 512 + l * 8;
#pragma unroll
    for (int nt = 0; nt < NT; nt++) {
      short8 bf = *(const short8*)(bbase + nt * 512);
      acc[nt] = __builtin_amdgcn_mfma_f32_16x16x32_bf16(af, bf, acc[nt], 0, 0, 0);
    }
  }

  if (EPI == 0) {
#pragma unroll
    for (int nt = 0; nt < NT; nt++) {
#pragma unroll
      for (int r = 0; r < 4; r++) {
        int row = row0 + quad * 4 + r;    // C/D: row = (lane>>4)*4 + reg, col = lane&15
        if (row < M) outb[(size_t)row * ND + nt * 16 + col0] = f2bf_bits(acc[nt][r]);
      }
    }
  } else {
    // KV split: K -> fp8, V -> bf16 (both row size 128)
#pragma unroll
    for (int nt = 0; nt < NT; nt++) {
#pragma unroll
      for (int r = 0; r < 4; r++) {
        int row = row0 + quad * 4 + r;
        if (row < M) {
          int c = nt * 16 + col0;
          if (c < 128) {
            int pk = __builtin_amdgcn_cvt_pk_fp8_f32(acc[nt][r], acc[nt][r], 0, false);
            outp8[(size_t)row * 128 + c] = (unsigned char)(pk & 0xff);
          } else {
            outb[(size_t)row * 128 + (c - 128)] = f2bf_bits(acc[nt][r]);
          }
        }
      }
    }
  }
}

// ---------------- attention: one wave per query, fp8 K gather, no-max softmax ----------------
// Softmax is shift-invariant; scores are O(+-10) so exp() in fp32 cannot overflow -> skip max pass.
__global__ __launch_bounds__(256) void attn_kernel(
    const unsigned short* __restrict__ Qb,    // [N_QUERY][128] bf16 (pre-scaled 1/sqrt(16))
    const unsigned char* __restrict__ Kp8,    // [N_ATOM][128] fp8 e4m3
    const unsigned short* __restrict__ Vb,    // [N_ATOM][128] bf16
    const float* __restrict__ edge_attr,      // [E][16]
    const float* __restrict__ Wrbf,           // [8][16]
    const int* __restrict__ src,              // [E]
    float* __restrict__ Agg) {                // [N_QUERY][128]
  const int l = threadIdx.x & 63;
  const int w = threadIdx.x >> 6;
  const int q = blockIdx.x * 4 + w;
  const int h  = l >> 3;          // head owning dims 2l,2l+1
  const int r8 = l & 7;

  unsigned int qu = ((const unsigned int*)(Qb + (size_t)q * 128))[l];
  float q0 = bflo(qu);
  float q1 = bfhi(qu);
  float2 wr = *(const float2*)(Wrbf + h * 16 + 2 * r8);

  const int e0 = q * KNN;
  int srcj = (l < KNN) ? src[e0 + l] : 0;

  float lsum = 0.f, acc0 = 0.f, acc1 = 0.f;
#pragma unroll 8
  for (int j = 0; j < KNN; j++) {
    int s = __shfl(srcj, j, 64);
    unsigned int ku = *(const unsigned short*)(Kp8 + (size_t)s * 128 + 2 * l);
    unsigned int vu = ((const unsigned int*)(Vb + (size_t)s * 128))[l];
    float2 ea = *(const float2*)(edge_attr + (size_t)(e0 + j) * 16 + 2 * r8);
    fx2 kf = __builtin_amdgcn_cvt_pk_f32_fp8((int)ku, false);
    float part = q0 * kf[0] + q1 * kf[1] + wr.x * ea.x + wr.y * ea.y;
    part += __shfl_xor(part, 1, 64);
    part += __shfl_xor(part, 2, 64);
    part += __shfl_xor(part, 4, 64);   // 8 lanes of head group hold score[j][h]
    float p = __expf(part);
    lsum += p;
    acc0 += p * bflo(vu);
    acc1 += p * bfhi(vu);
  }
  float inv = 1.f / (lsum + 1e-16f);
  float2 ag; ag.x = acc0 * inv; ag.y = acc1 * inv;
  *(float2*)(Agg + (size_t)q * 128 + 2 * l) = ag;
}

// ---------------- fused MLP: relu([h_query|Agg]@W1^T+b1) @ W2^T + b2 + resid -> LayerNorm -------
// 4 waves/block, 64 rows/block. Hidden tile round-trips through LDS (bf16, row stride 272B:
// 16B-aligned for ds_read_b128, bank stride 68%32=4 -> 2 lanes/bank = free).
__global__ __launch_bounds__(256) void mlp_kernel(
    const float* __restrict__ h_query, const float* __restrict__ Agg,
    const unsigned short* __restrict__ W1p, const unsigned short* __restrict__ W2p,
    const float* __restrict__ b1, const float* __restrict__ b2,
    const float* __restrict__ gamma, const float* __restrict__ beta,
    float* __restrict__ out) {
  constexpr int M = N_QUERY;
  constexpr int STRIDE = 136;               // ushorts per LDS row (272 B)
  __shared__ unsigned short hid[64 * STRIDE];

  const int l    = threadIdx.x & 63;
  const int w    = threadIdx.x >> 6;
  const int quad = l >> 4;
  const int col0 = l & 15;
  const int row0 = blockIdx.x * 64 + w * 16;
  int arow = row0 + col0;
  if (arow >= M) arow = M - 1;

  // ---- stage 1: hidden = relu([h_query | Agg] @ W1^T + b1) ----
  floatx4 acc[8];
#pragma unroll
  for (int i = 0; i < 8; i++) acc[i] = (floatx4){0.f, 0.f, 0.f, 0.f};
#pragma unroll
  for (int k0 = 0; k0 < 256; k0 += 32) {
    const float* sp = (k0 < 128) ? (h_query + (size_t)arow * 128 + k0)
                                 : (Agg + (size_t)arow * 128 + (k0 - 128));
    floatx4 a0 = *(const floatx4*)(sp + quad * 8);
    floatx4 a1 = *(const floatx4*)(sp + quad * 8 + 4);
    short8 af;
    af[0] = (short)f2bf_bits(a0[0]); af[1] = (short)f2bf_bits(a0[1]);
    af[2] = (short)f2bf_bits(a0[2]); af[3] = (short)f2bf_bits(a0[3]);
    af[4] = (short)f2bf_bits(a1[0]); af[5] = (short)f2bf_bits(a1[1]);
    af[6] = (short)f2bf_bits(a1[2]); af[7] = (short)f2bf_bits(a1[3]);
    const unsigned short* bbase = W1p + (size_t)(k0 >> 5) * 8 * 512 + l * 8;
#pragma unroll
    for (int nt = 0; nt < 8; nt++) {
      short8 bf = *(const short8*)(bbase + nt * 512);
      acc[nt] = __builtin_amdgcn_mfma_f32_16x16x32_bf16(af, bf, acc[nt], 0, 0, 0);
    }
  }
#pragma unroll
  for (int nt = 0; nt < 8; nt++) {
#pragma unroll
    for (int r = 0; r < 4; r++) {
      int rl = w * 16 + quad * 4 + r;       // local row in block tile
      float v = acc[nt][r] + b1[nt * 16 + col0];
      hid[rl * STRIDE + nt * 16 + col0] = f2bf_bits(fmaxf(v, 0.f));
    }
  }
  __syncthreads();

  // ---- stage 2: out = LN(hidden @ W2^T + b2 + h_query) ----
  floatx4 acc2[8];
#pragma unroll
  for (int i = 0; i < 8; i++) acc2[i] = (floatx4){0.f, 0.f, 0.f, 0.f};
  const int rloc = w * 16 + col0;           // A-frag row (local)
#pragma unroll
  for (int k0 = 0; k0 < 128; k0 += 32) {
    short8 af = *(const short8*)(hid + rloc * STRIDE + k0 + quad * 8);
    const unsigned short* bbase = W2p + (size_t)(k0 >> 5) * 8 * 512 + l * 8;
#pragma unroll
    for (int nt = 0; nt < 8; nt++) {
      short8 bf = *(const short8*)(bbase + nt * 512);
      acc2[nt] = __builtin_amdgcn_mfma_f32_16x16x32_bf16(af, bf, acc2[nt], 0, 0, 0);
    }
  }

#pragma unroll
  for (int r = 0; r < 4; r++) {
    int row = row0 + quad * 4 + r;
    int rr  = row < M ? row : M - 1;
    float v[8];
    float s1 = 0.f, s2 = 0.f;
#pragma unroll
    for (int nt = 0; nt < 8; nt++) {
      int c = nt * 16 + col0;
      v[nt] = acc2[nt][r] + b2[c] + h_query[(size_t)rr * 128 + c];
      s1 += v[nt];
    }
    s1 += __shfl_xor(s1, 1, 64); s1 += __shfl_xor(s1, 2, 64);
    s1 += __shfl_xor(s1, 4, 64); s1 += __shfl_xor(s1, 8, 64);
#pragma unroll
    for (int nt = 0; nt < 8; nt++) s2 += v[nt] * v[nt];
    s2 += __shfl_xor(s2, 1, 64); s2 += __shfl_xor(s2, 2, 64);
    s2 += __shfl_xor(s2, 4, 64); s2 += __shfl_xor(s2, 8, 64);
    float mean = s1 * (1.0f / 128.0f);
    float var  = s2 * (1.0f / 128.0f) - mean * mean;
    float rstd = rsqrtf(var + 1e-5f);
    if (row < M) {
#pragma unroll
      for (int nt = 0; nt < 8; nt++) {
        int c = nt * 16 + col0;
        out[(size_t)row * 128 + c] = (v[nt] - mean) * rstd * gamma[c] + beta[c];
      }
    }
  }
}

extern "C" void kernel_launch(void* const* d_in, const int* in_sizes, int n_in,
                              void* d_out, int out_size, void* d_ws, size_t ws_size,
                              hipStream_t stream) {
  const float* h_atom    = (const float*)d_in[0];
  const float* h_query   = (const float*)d_in[1];
  const float* edge_attr = (const float*)d_in[2];
  const float* W_q  = (const float*)d_in[3];
  const float* W_k  = (const float*)d_in[4];
  const float* W_v  = (const float*)d_in[5];
  const float* Wrbf = (const float*)d_in[6];
  const float* W1   = (const float*)d_in[7];
  const float* b1   = (const float*)d_in[8];
  const float* W2   = (const float*)d_in[9];
  const float* b2   = (const float*)d_in[10];
  const float* ln_g = (const float*)d_in[11];
  const float* ln_b = (const float*)d_in[12];
  const int* edge_index = (const int*)d_in[13];   // [0..E) = src
  float* out = (float*)d_out;

  char* ws = (char*)d_ws;
  unsigned char*  Kp8 = (unsigned char*)(ws);                  // 100000*128 B   = 12.8 MB
  unsigned short* Vb  = (unsigned short*)(ws + 12800000);      // 100000*128 bf16= 25.6 MB
  unsigned short* Qb  = (unsigned short*)(ws + 38400000);      // 20000*128 bf16 = 5.12 MB
  float* Agg          = (float*)(ws + 43520000);               // 20000*128 f32  = 10.24 MB
  unsigned short* WKVp = (unsigned short*)(ws + 53760000);     // 128x256
  unsigned short* WQp  = WKVp + 32768;                         // 128x128
  unsigned short* W1p  = WQp  + 16384;                         // 256x128
  unsigned short* W2p  = W1p  + 32768;                         // 128x128

  pack_all_kernel<<<(98304 + 255) / 256, 256, 0, stream>>>(
      W_q, W_k, W_v, W1, W2, WKVp, WQp, W1p, W2p);

  // K(fp8) / V(bf16) = h_atom @ [W_k|W_v]^T
  gemm_k<128, 16, 3><<<(N_ATOM + 63) / 64, 256, 0, stream>>>(
      h_atom, WKVp, N_ATOM, Vb, Kp8);
  // Q = h_query @ (W_q/4)^T -> bf16
  gemm_k<128, 8, 0><<<(N_QUERY + 63) / 64, 256, 0, stream>>>(
      h_query, WQp, N_QUERY, Qb, nullptr);
  // attention -> Agg
  attn_kernel<<<N_QUERY / 4, 256, 0, stream>>>(Qb, Kp8, Vb, edge_attr, Wrbf, edge_index, Agg);
  // fused MLP + residual + LayerNorm -> out
  mlp_kernel<<<(N_QUERY + 63) / 64, 256, 0, stream>>>(
      h_query, Agg, W1p, W2p, b1, b2, ln_g, ln_b, out);
}